// Round 10
// baseline (327.955 us; speedup 1.0000x reference)
//
#include <hip/hip_runtime.h>

#define NN 100000
#define NE 1600000
#define DH 128
#define NG 64

#define NBUCK 391          // ceil(NN/256) buckets, bucket = dst >> 8
#define EPB 4096           // edges per build block
#define NBLK_BIN 391       // ceil(NE/EPB)
#define CAP 5120           // pairs capacity per bucket (mean 4092, sigma~64)

#define LDH 136            // padded halves per LDS row
#define LDF 132            // padded floats per LDS row (fp32 stage, bank-spread)

typedef __attribute__((ext_vector_type(2))) _Float16 half2v;
typedef __attribute__((ext_vector_type(4))) _Float16 half4;
typedef __attribute__((ext_vector_type(8))) _Float16 half8;
typedef __attribute__((ext_vector_type(4))) float f32x4;

// e5m2 encode: RNE-round fp16 to top byte.
__device__ inline unsigned int enc8(_Float16 h) {
  unsigned short b = __builtin_bit_cast(unsigned short, h);
  unsigned short r = (unsigned short)(b + 0x7F + ((b >> 8) & 1));
  return (unsigned int)(r >> 8);
}
// decode 4 e5m2 bytes -> two half2: {dim0,dim2} and {dim1,dim3}
__device__ inline half2v d02(unsigned int u) {
  return __builtin_bit_cast(half2v, (u << 8) & 0xFF00FF00u);
}
__device__ inline half2v d13(unsigned int u) {
  return __builtin_bit_cast(half2v, u & 0xFF00FF00u);
}

#define DEC4(u)                                                                         \
  acc[0] += d02(u.x); acc[1] += d13(u.x); acc[2] += d02(u.y); acc[3] += d13(u.y);       \
  acc[4] += d02(u.z); acc[5] += d13(u.z); acc[6] += d02(u.w); acc[7] += d13(u.w);

// Pipelined gather: 2 groups of 4 uint4 gathers in flight, idx prefetched
// one group further ahead (proven R5/R6: 54.5 -> 50.0 us on k_fused).
__device__ inline void gather_rows(const unsigned char* __restrict__ bp,
                                   const int* __restrict__ csr_src,
                                   int p, int e, half2v (&acc)[8]) {
  if (p + 3 < e) {
    int j0 = csr_src[p], j1 = csr_src[p + 1], j2 = csr_src[p + 2], j3 = csr_src[p + 3];
    uint4 c0 = *(const uint4*)(bp + (size_t)j0 * DH);
    uint4 c1 = *(const uint4*)(bp + (size_t)j1 * DH);
    uint4 c2 = *(const uint4*)(bp + (size_t)j2 * DH);
    uint4 c3 = *(const uint4*)(bp + (size_t)j3 * DH);
    p += 4;
    int pb = (p + 3 < e) ? p : p - 4;        // clamped idx prefetch (no OOB)
    j0 = csr_src[pb]; j1 = csr_src[pb + 1]; j2 = csr_src[pb + 2]; j3 = csr_src[pb + 3];
    while (p + 3 < e) {
      uint4 n0 = *(const uint4*)(bp + (size_t)j0 * DH);   // data grp k+1 (idx ready)
      uint4 n1 = *(const uint4*)(bp + (size_t)j1 * DH);
      uint4 n2 = *(const uint4*)(bp + (size_t)j2 * DH);
      uint4 n3 = *(const uint4*)(bp + (size_t)j3 * DH);
      p += 4;
      int pb2 = (p + 3 < e) ? p : p - 4;                  // idx grp k+2
      j0 = csr_src[pb2]; j1 = csr_src[pb2 + 1]; j2 = csr_src[pb2 + 2]; j3 = csr_src[pb2 + 3];
      DEC4(c0); DEC4(c1); DEC4(c2); DEC4(c3);             // decode grp k
      c0 = n0; c1 = n1; c2 = n2; c3 = n3;
    }
    DEC4(c0); DEC4(c1); DEC4(c2); DEC4(c3);
  }
  for (; p < e; ++p) {
    uint4 u0 = *(const uint4*)(bp + (size_t)csr_src[p] * DH);
    DEC4(u0);
  }
}

// ---------------- build: LDS hist -> atomic range reservation -> place ------
// Bucketed (bucket = dst>>8, 391 buckets): confines pairs/csr scatters to
// 20KB L2-resident windows (R7: unbucketed scatter = 3x worse via write
// amplification). No W-transpose here anymore: its 34.8KB LDS tile capped
// occupancy at 4 blocks/CU; without it LDS=3.1KB -> 8 blocks/CU.

__global__ __launch_bounds__(256) void k_build(const int* __restrict__ esrc,
                                               const int* __restrict__ edst,
                                               const int* __restrict__ batch,
                                               int* __restrict__ bucketCursor,
                                               unsigned int* __restrict__ pairs,
                                               int* __restrict__ startg) {
  __shared__ int h[NBUCK];
  __shared__ int cur[NBUCK];
  int b = blockIdx.x, t = threadIdx.x;
  int gtid = b * 256 + t;

  if (gtid < NN) {
    int bat = batch[gtid];
    int prev = (gtid == 0) ? -1 : batch[gtid - 1];
    for (int g = prev + 1; g <= bat; ++g) startg[g] = gtid;
    if (gtid == NN - 1)
      for (int g = bat + 1; g <= NG; ++g) startg[g] = NN;
  }

  for (int i = t; i < NBUCK; i += 256) h[i] = 0;
  __syncthreads();
  int base = b * EPB;
  int dv[EPB / 256];   // cache dst values: placement pass re-uses w/o re-load
#pragma unroll
  for (int i = 0; i < EPB / 256; ++i) {
    int e = base + i * 256 + t;
    dv[i] = (e < NE) ? edst[e] : -1;
    if (e < NE) atomicAdd(&h[dv[i] >> 8], 1);
  }
  __syncthreads();
  for (int i = t; i < NBUCK; i += 256) {
    int rel = atomicAdd(&bucketCursor[i], h[i]);   // reserve contiguous range
    cur[i] = i * CAP + rel;
  }
  __syncthreads();
#pragma unroll
  for (int i = 0; i < EPB / 256; ++i) {
    int e = base + i * 256 + t;
    if (e < NE) {
      int d = dv[i];
      int q = atomicAdd(&cur[d >> 8], 1);
      pairs[q] = ((unsigned int)esrc[e] << 8) | (unsigned int)(d & 255);
    }
  }
}

// ---------------- finalize: per-bucket count/scan -> offA/offB/dinv + csr ---
// 391 main blocks (full GPU). Tail blocks 391-393: W transpose via direct
// scatter (96KB total into L2-resident Wt, lines fully overwritten -> L2
// merges; nothing like R7's 1.6M-random-scatter failure).

__global__ __launch_bounds__(256) void k_finalize(const unsigned int* __restrict__ pairs,
                                                  const int* __restrict__ bucketCursor,
                                                  const float* __restrict__ W0,
                                                  const float* __restrict__ W1,
                                                  const float* __restrict__ W2,
                                                  _Float16* __restrict__ Wt,
                                                  int* __restrict__ offA,
                                                  int* __restrict__ offB,
                                                  float* __restrict__ dinv,
                                                  int* __restrict__ csr_src) {
  __shared__ int cnt[256];
  __shared__ int tsum[256];
  int b = blockIdx.x, t = threadIdx.x;

  if (b >= NBUCK) {   // W transpose tail blocks
    int l = b - NBUCK;
    const float* W = (l == 0) ? W0 : (l == 1) ? W1 : W2;
#pragma unroll
    for (int i = 0; i < 64; ++i) {
      int idx = i * 256 + t;
      int r = idx >> 7, c = idx & 127;
      Wt[(size_t)l * DH * DH + c * DH + r] = (_Float16)W[r * DH + c];
    }
    return;
  }

  int g = (b << 8) + t;
  cnt[t] = 0;
  __syncthreads();
  int pStart = b * CAP;
  int pEnd = pStart + bucketCursor[b];
  for (int p = pStart + t; p < pEnd; p += 256)
    atomicAdd(&cnt[pairs[p] & 255], 1);
  __syncthreads();
  int c = cnt[t];
  tsum[t] = c;
  __syncthreads();
  for (int off = 1; off < 256; off <<= 1) {
    int v = (t >= off) ? tsum[t - off] : 0;
    __syncthreads();
    tsum[t] += v;
    __syncthreads();
  }
  int basep = pStart + ((t > 0) ? tsum[t - 1] : 0);
  if (g < NN) {
    offA[g] = basep;
    offB[g] = basep + c;
    dinv[g] = rsqrtf((float)c + 1.f);
  }
  cnt[t] = basep;
  __syncthreads();
  for (int p = pStart + t; p < pEnd; p += 256) {
    unsigned int pr = pairs[p];
    int pos = atomicAdd(&cnt[pr & 255], 1);
    csr_src[pos] = (int)(pr >> 8);
  }
}

// ---------------- MFMA GEMM (layer 1): Out8 = e5m2(dinv[r]*(x @ W1)) --------

template <bool F32IN>
__global__ __launch_bounds__(256) void k_gemm(const void* __restrict__ Ap,
                                              const _Float16* __restrict__ Wt,
                                              const float* __restrict__ dinv,
                                              unsigned char* __restrict__ Out8) {
  __shared__ _Float16 Wl[128 * LDH];
  int tid = threadIdx.x;
  int rowBase = blockIdx.x * 128;

#pragma unroll
  for (int i = 0; i < 8; ++i) {
    int chunk = tid + i * 256;
    int r = chunk >> 4, c = (chunk & 15) * 8;
    *(half8*)&Wl[r * LDH + c] = *(const half8*)(Wt + r * DH + c);
  }

  int wv = tid >> 6;
  int lane = tid & 63;
  int n16 = lane & 15;
  int quad = lane >> 4;

  int r0 = rowBase + wv * 32 + n16;
  int r1 = r0 + 16;

  half8 af[2][4];
  if (F32IN) {
    const float* A = (const float*)Ap;
#pragma unroll
    for (int kk = 0; kk < 4; ++kk) {
      half8 z = {};
      if (r0 < NN) {
        float4 lo = *(const float4*)(A + (size_t)r0 * DH + quad * 8 + kk * 32);
        float4 hi = *(const float4*)(A + (size_t)r0 * DH + quad * 8 + kk * 32 + 4);
        z = (half8){(_Float16)lo.x, (_Float16)lo.y, (_Float16)lo.z, (_Float16)lo.w,
                    (_Float16)hi.x, (_Float16)hi.y, (_Float16)hi.z, (_Float16)hi.w};
      }
      af[0][kk] = z;
      half8 z1 = {};
      if (r1 < NN) {
        float4 lo = *(const float4*)(A + (size_t)r1 * DH + quad * 8 + kk * 32);
        float4 hi = *(const float4*)(A + (size_t)r1 * DH + quad * 8 + kk * 32 + 4);
        z1 = (half8){(_Float16)lo.x, (_Float16)lo.y, (_Float16)lo.z, (_Float16)lo.w,
                     (_Float16)hi.x, (_Float16)hi.y, (_Float16)hi.z, (_Float16)hi.w};
      }
      af[1][kk] = z1;
    }
  } else {
    const _Float16* A = (const _Float16*)Ap;
#pragma unroll
    for (int kk = 0; kk < 4; ++kk) {
      half8 z = {};
      if (r0 < NN) z = *(const half8*)(A + (size_t)r0 * DH + quad * 8 + kk * 32);
      af[0][kk] = z;
      half8 z1 = {};
      if (r1 < NN) z1 = *(const half8*)(A + (size_t)r1 * DH + quad * 8 + kk * 32);
      af[1][kk] = z1;
    }
  }
  __syncthreads();

  f32x4 acc[2][8];
#pragma unroll
  for (int mt = 0; mt < 2; ++mt)
#pragma unroll
    for (int ct = 0; ct < 8; ++ct) acc[mt][ct] = (f32x4){0.f, 0.f, 0.f, 0.f};

  const _Float16* bp = &Wl[n16 * LDH + quad * 8];
#pragma unroll
  for (int kk = 0; kk < 4; ++kk) {
#pragma unroll
    for (int ct = 0; ct < 8; ++ct) {
      half8 bf = *(const half8*)(bp + (size_t)ct * 16 * LDH + kk * 32);
      acc[0][ct] = __builtin_amdgcn_mfma_f32_16x16x32_f16(af[0][kk], bf, acc[0][ct], 0, 0, 0);
      acc[1][ct] = __builtin_amdgcn_mfma_f32_16x16x32_f16(af[1][kk], bf, acc[1][ct], 0, 0, 0);
    }
  }

  float dv[2][4];
#pragma unroll
  for (int mt = 0; mt < 2; ++mt)
#pragma unroll
    for (int r = 0; r < 4; ++r) {
      int gr = rowBase + wv * 32 + mt * 16 + quad * 4 + r;
      dv[mt][r] = (gr < NN) ? dinv[gr] : 0.f;
    }

  __syncthreads();
#pragma unroll
  for (int mt = 0; mt < 2; ++mt)
#pragma unroll
    for (int ct = 0; ct < 8; ++ct)
#pragma unroll
      for (int r = 0; r < 4; ++r)
        Wl[(wv * 32 + mt * 16 + quad * 4 + r) * LDH + ct * 16 + n16] =
            (_Float16)(acc[mt][ct][r] * dv[mt][r]);
  __syncthreads();

#pragma unroll
  for (int i = 0; i < 8; ++i) {
    int chunk = tid + i * 256;
    int r = chunk >> 4, c = (chunk & 15) * 8;
    int gr = rowBase + r;
    if (gr < NN) {
      half8 v = *(const half8*)&Wl[r * LDH + c];
      unsigned int lo = enc8(v[0]) | (enc8(v[1]) << 8) | (enc8(v[2]) << 16) | (enc8(v[3]) << 24);
      unsigned int hi = enc8(v[4]) | (enc8(v[5]) << 8) | (enc8(v[6]) << 16) | (enc8(v[7]) << 24);
      uint2 st = {lo, hi};
      *(uint2*)(Out8 + (size_t)gr * DH + c) = st;
    }
  }
}

// ---------------- fused aggregate_L + pool_L + GEMM_{L+1} ----------------

__global__ __launch_bounds__(512) void k_fused(const unsigned char* __restrict__ hs8_in,
                                               const int* __restrict__ csr_src,
                                               const int* __restrict__ offA,
                                               const int* __restrict__ offB,
                                               const float* __restrict__ dinv,
                                               const float* __restrict__ bias,
                                               const int* __restrict__ batch,
                                               const int* __restrict__ startg,
                                               float* __restrict__ pooled,
                                               int colOff,
                                               const _Float16* __restrict__ Wt,
                                               unsigned char* __restrict__ hs8_out) {
  __shared__ _Float16 Hl[64 * LDH];
  __shared__ _Float16 Wl[128 * LDH];
  int tid = threadIdx.x;
  int n0 = blockIdx.x * 64;

#pragma unroll
  for (int i = 0; i < 4; ++i) {
    int chunk = tid + i * 512;
    int r = chunk >> 4, c = (chunk & 15) * 8;
    *(half8*)&Wl[r * LDH + c] = *(const half8*)(Wt + r * DH + c);
  }

  int nd = tid >> 3;
  int part = tid & 7;
  int n = n0 + nd;
  bool valid = (n < NN);

  half2v acc[8];
#pragma unroll
  for (int i = 0; i < 8; ++i) acc[i] = (half2v){(_Float16)0, (_Float16)0};

  if (valid) {
    const unsigned char* bp = hs8_in + part * 16;
    uint4 us = *(const uint4*)(bp + (size_t)n * DH);
    DEC4(us);
    gather_rows(bp, csr_src, offA[n], offB[n], acc);
  }

  float dv = valid ? dinv[n] : 0.f;
#pragma unroll
  for (int w = 0; w < 4; ++w) {
    int dim = part * 16 + w * 4;
    float4 b4 = *(const float4*)(bias + dim);
    float h0 = valid ? fmaxf(fmaf((float)acc[2 * w][0], dv, b4.x), 0.f) : 0.f;
    float h1 = valid ? fmaxf(fmaf((float)acc[2 * w + 1][0], dv, b4.y), 0.f) : 0.f;
    float h2 = valid ? fmaxf(fmaf((float)acc[2 * w][1], dv, b4.z), 0.f) : 0.f;
    float h3 = valid ? fmaxf(fmaf((float)acc[2 * w + 1][1], dv, b4.w), 0.f) : 0.f;
    half4 hh = {(_Float16)h0, (_Float16)h1, (_Float16)h2, (_Float16)h3};
    *(half4*)&Hl[nd * LDH + dim] = hh;
  }
  __syncthreads();

  if (tid < DH) {
    int nEnd = (n0 + 64 < NN) ? n0 + 64 : NN;
    int gF = batch[n0];
    int gL = batch[nEnd - 1];
    for (int g = gF; g <= gL; ++g) {
      int rs = (startg[g] > n0) ? startg[g] : n0;
      int re = (startg[g + 1] < nEnd) ? startg[g + 1] : nEnd;
      if (re > rs) {
        float sum = 0.f;
        for (int r2 = rs; r2 < re; ++r2) sum += (float)Hl[(r2 - n0) * LDH + tid];
        atomicAdd(&pooled[g * (3 * DH) + colOff + tid], sum);
      }
    }
  }

  int wv = tid >> 6;
  int lane = tid & 63;
  int n16 = lane & 15;
  int quad = lane >> 4;
  int m16 = wv >> 1;
  int ctB = (wv & 1) * 4;

  f32x4 acc2[4];
#pragma unroll
  for (int ct = 0; ct < 4; ++ct) acc2[ct] = (f32x4){0.f, 0.f, 0.f, 0.f};

  const _Float16* ap = &Hl[(m16 * 16 + n16) * LDH + quad * 8];
#pragma unroll
  for (int kk = 0; kk < 4; ++kk) {
    half8 af = *(const half8*)(ap + kk * 32);
#pragma unroll
    for (int ct = 0; ct < 4; ++ct) {
      half8 bf = *(const half8*)&Wl[((ctB + ct) * 16 + n16) * LDH + quad * 8 + kk * 32];
      acc2[ct] = __builtin_amdgcn_mfma_f32_16x16x32_f16(af, bf, acc2[ct], 0, 0, 0);
    }
  }

  float dvo[4];
#pragma unroll
  for (int rr = 0; rr < 4; ++rr) {
    int gr = n0 + m16 * 16 + quad * 4 + rr;
    dvo[rr] = (gr < NN) ? dinv[gr] : 0.f;
  }

  __syncthreads();
#pragma unroll
  for (int ct = 0; ct < 4; ++ct)
#pragma unroll
    for (int rr = 0; rr < 4; ++rr)
      Hl[(m16 * 16 + quad * 4 + rr) * LDH + (ctB + ct) * 16 + n16] =
          (_Float16)(acc2[ct][rr] * dvo[rr]);
  __syncthreads();

#pragma unroll
  for (int i = 0; i < 2; ++i) {
    int chunk = tid + i * 512;
    int r = chunk >> 4, c = (chunk & 15) * 8;
    int gr = n0 + r;
    if (gr < NN) {
      half8 v = *(const half8*)&Hl[r * LDH + c];
      unsigned int lo = enc8(v[0]) | (enc8(v[1]) << 8) | (enc8(v[2]) << 16) | (enc8(v[3]) << 24);
      unsigned int hi = enc8(v[4]) | (enc8(v[5]) << 8) | (enc8(v[6]) << 16) | (enc8(v[7]) << 24);
      uint2 st = {lo, hi};
      *(uint2*)(hs8_out + (size_t)gr * DH + c) = st;
    }
  }
}

// ---------------- final aggregate + pool (pipelined gather) ----------------

__global__ __launch_bounds__(512) void k_aggregate(const unsigned char* __restrict__ hs8,
                                                   const int* __restrict__ csr_src,
                                                   const int* __restrict__ offA,
                                                   const int* __restrict__ offB,
                                                   const float* __restrict__ dinv,
                                                   const float* __restrict__ bias,
                                                   const int* __restrict__ batch,
                                                   const int* __restrict__ startg,
                                                   float* __restrict__ pooled,
                                                   int colOff) {
  __shared__ float stage[64][LDF];   // LDF=132 pad: spreads part-lanes across banks
  int tid = threadIdx.x;
  int n0 = blockIdx.x * 64;
  int nd = tid >> 3;
  int part = tid & 7;
  int n = n0 + nd;
  bool valid = (n < NN);

  half2v acc[8];
#pragma unroll
  for (int i = 0; i < 8; ++i) acc[i] = (half2v){(_Float16)0, (_Float16)0};

  if (valid) {
    const unsigned char* bp = hs8 + part * 16;
    uint4 us = *(const uint4*)(bp + (size_t)n * DH);
    DEC4(us);
    gather_rows(bp, csr_src, offA[n], offB[n], acc);
  }

  float dv = valid ? dinv[n] : 0.f;
#pragma unroll
  for (int w = 0; w < 4; ++w) {
    int dim = part * 16 + w * 4;
    float4 b4 = *(const float4*)(bias + dim);
    float4 r;
    r.x = valid ? fmaxf(fmaf((float)acc[2 * w][0], dv, b4.x), 0.f) : 0.f;
    r.y = valid ? fmaxf(fmaf((float)acc[2 * w + 1][0], dv, b4.y), 0.f) : 0.f;
    r.z = valid ? fmaxf(fmaf((float)acc[2 * w][1], dv, b4.z), 0.f) : 0.f;
    r.w = valid ? fmaxf(fmaf((float)acc[2 * w + 1][1], dv, b4.w), 0.f) : 0.f;
    *(float4*)&stage[nd][dim] = r;
  }
  __syncthreads();

  if (tid < DH) {
    int nEnd = (n0 + 64 < NN) ? n0 + 64 : NN;
    int gF = batch[n0];
    int gL = batch[nEnd - 1];
    for (int g = gF; g <= gL; ++g) {
      int rs = (startg[g] > n0) ? startg[g] : n0;
      int re = (startg[g + 1] < nEnd) ? startg[g + 1] : nEnd;
      if (re > rs) {
        float sum = 0.f;
        for (int r2 = rs; r2 < re; ++r2) sum += stage[r2 - n0][tid];
        atomicAdd(&pooled[g * (3 * DH) + colOff + tid], sum);
      }
    }
  }
}

// ---------------- head ----------------

__global__ __launch_bounds__(128) void k_head(const float* __restrict__ pooled,
                                              const int* __restrict__ startg,
                                              const float* __restrict__ l1w,
                                              const float* __restrict__ l1b,
                                              const float* __restrict__ l2w,
                                              const float* __restrict__ l2b,
                                              float* __restrict__ out) {
  __shared__ float pr[3 * DH];
  __shared__ float grow[DH];
  __shared__ float lg[16];
  int g = blockIdx.x, t = threadIdx.x;
  float cnt = (float)(startg[g + 1] - startg[g]);
  float inv = 1.0f / fmaxf(cnt, 1.0f);
  for (int k = t; k < 3 * DH; k += 128) pr[k] = pooled[g * (3 * DH) + k] * inv;
  __syncthreads();
  float acc = l1b[t];
  for (int k = 0; k < 3 * DH; ++k) acc = fmaf(pr[k], l1w[k * DH + t], acc);
  grow[t] = fmaxf(acc, 0.f);
  __syncthreads();
  if (t < 10) {
    float a = l2b[t];
    for (int k = 0; k < DH; ++k) a = fmaf(grow[k], l2w[k * 10 + t], a);
    lg[t] = a;
  }
  __syncthreads();
  if (t < 10) {
    float m = lg[0];
    for (int i = 1; i < 10; ++i) m = fmaxf(m, lg[i]);
    float sum = 0.f;
    for (int i = 0; i < 10; ++i) sum += expf(lg[i] - m);
    out[g * 10 + t] = lg[t] - m - logf(sum);
  }
}

// ---------------- launch ----------------

extern "C" void kernel_launch(void* const* d_in, const int* in_sizes, int n_in,
                              void* d_out, int out_size, void* d_ws, size_t ws_size,
                              hipStream_t stream) {
  const float* x = (const float*)d_in[0];
  const int* ei = (const int*)d_in[1];
  const int* esrc = ei;
  const int* edst = ei + NE;
  const int* batch = (const int*)d_in[2];
  const float* W0 = (const float*)d_in[4];
  const float* W1 = (const float*)d_in[6];
  const float* W2 = (const float*)d_in[8];
  const float* B[3] = {(const float*)d_in[5], (const float*)d_in[7], (const float*)d_in[9]};
  const float* l1w = (const float*)d_in[10];
  const float* l1b = (const float*)d_in[11];
  const float* l2w = (const float*)d_in[12];
  const float* l2b = (const float*)d_in[13];
  float* out = (float*)d_out;

  char* ws = (char*)d_ws;
  size_t off = 0;
  auto alloc = [&](size_t bytes) {
    char* p = ws + off;
    off = (off + bytes + 255) & ~(size_t)255;
    return p;
  };
  // memset region: pooled + bucketCursor (contiguous)
  float* pooled = (float*)alloc((size_t)NG * 3 * DH * 4);        // 98304 B
  int* bucketCursor = (int*)alloc(NBUCK * 4);                    // 1564 -> pad
  size_t msBytes = ((size_t)NG * 3 * DH * 4 + NBUCK * 4 + 255) & ~(size_t)255;

  int* offA = (int*)alloc((size_t)NN * 4);
  int* offB = (int*)alloc((size_t)NN * 4);
  float* dinv = (float*)alloc((size_t)NN * 4);
  int* startg = (int*)alloc((NG + 1) * 4);
  _Float16* Wt = (_Float16*)alloc((size_t)3 * DH * DH * 2);
  unsigned char* hs8A = (unsigned char*)alloc((size_t)NN * DH);
  unsigned char* hs8B = (unsigned char*)alloc((size_t)NN * DH);
  unsigned int* pairs = (unsigned int*)alloc((size_t)NBUCK * CAP * 4);
  int* csr_src = (int*)alloc((size_t)NBUCK * CAP * 4);

  hipMemsetAsync(pooled, 0, msBytes, stream);

  k_build<<<NBLK_BIN, 256, 0, stream>>>(esrc, edst, batch, bucketCursor, pairs, startg);
  k_finalize<<<NBUCK + 3, 256, 0, stream>>>(pairs, bucketCursor, W0, W1, W2, Wt,
                                            offA, offB, dinv, csr_src);

  k_gemm<true><<<(NN + 127) / 128, 256, 0, stream>>>((const void*)x, Wt, dinv, hs8A);

  int nFusedBlk = (NN + 63) / 64;
  k_fused<<<nFusedBlk, 512, 0, stream>>>(hs8A, csr_src, offA, offB, dinv, B[0], batch,
                                         startg, pooled, 0,
                                         Wt + (size_t)1 * DH * DH, hs8B);
  k_fused<<<nFusedBlk, 512, 0, stream>>>(hs8B, csr_src, offA, offB, dinv, B[1], batch,
                                         startg, pooled, DH,
                                         Wt + (size_t)2 * DH * DH, hs8A);

  k_aggregate<<<nFusedBlk, 512, 0, stream>>>(hs8A, csr_src, offA, offB, dinv, B[2],
                                             batch, startg, pooled, 2 * DH);

  k_head<<<NG, 128, 0, stream>>>(pooled, startg, l1w, l1b, l2w, l2b, out);
}

// Round 11
// 313.533 us; speedup vs baseline: 1.0460x; 1.0460x over previous
//
#include <hip/hip_runtime.h>

#define NN 100000
#define NE 1600000
#define DH 128
#define NG 64

#define NBUCK 391          // ceil(NN/256) buckets, bucket = dst >> 8
#define EPB 4096           // edges per build block
#define NBLK_BIN 391       // ceil(NE/EPB)
#define CAP 5120           // pairs capacity per bucket (mean 4092, sigma~64)

#define LDH 136            // padded halves per LDS row
#define LDF 132            // padded floats per LDS row (fp32 stage, bank-spread)

typedef __attribute__((ext_vector_type(2))) _Float16 half2v;
typedef __attribute__((ext_vector_type(4))) _Float16 half4;
typedef __attribute__((ext_vector_type(8))) _Float16 half8;
typedef __attribute__((ext_vector_type(4))) float f32x4;

// e5m2 encode: RNE-round fp16 to top byte.
__device__ inline unsigned int enc8(_Float16 h) {
  unsigned short b = __builtin_bit_cast(unsigned short, h);
  unsigned short r = (unsigned short)(b + 0x7F + ((b >> 8) & 1));
  return (unsigned int)(r >> 8);
}
// decode 4 e5m2 bytes -> two half2: {dim0,dim2} and {dim1,dim3}
__device__ inline half2v d02(unsigned int u) {
  return __builtin_bit_cast(half2v, (u << 8) & 0xFF00FF00u);
}
__device__ inline half2v d13(unsigned int u) {
  return __builtin_bit_cast(half2v, u & 0xFF00FF00u);
}

#define DEC4(u)                                                                         \
  acc[0] += d02(u.x); acc[1] += d13(u.x); acc[2] += d02(u.y); acc[3] += d13(u.y);       \
  acc[4] += d02(u.z); acc[5] += d13(u.z); acc[6] += d02(u.w); acc[7] += d13(u.w);

// Pipelined gather: 2 groups of 4 uint4 gathers in flight, idx prefetched
// one group further ahead (proven R5/R6: 54.5 -> 50.0 us on k_fused).
__device__ inline void gather_rows(const unsigned char* __restrict__ bp,
                                   const int* __restrict__ csr_src,
                                   int p, int e, half2v (&acc)[8]) {
  if (p + 3 < e) {
    int j0 = csr_src[p], j1 = csr_src[p + 1], j2 = csr_src[p + 2], j3 = csr_src[p + 3];
    uint4 c0 = *(const uint4*)(bp + (size_t)j0 * DH);
    uint4 c1 = *(const uint4*)(bp + (size_t)j1 * DH);
    uint4 c2 = *(const uint4*)(bp + (size_t)j2 * DH);
    uint4 c3 = *(const uint4*)(bp + (size_t)j3 * DH);
    p += 4;
    int pb = (p + 3 < e) ? p : p - 4;        // clamped idx prefetch (no OOB)
    j0 = csr_src[pb]; j1 = csr_src[pb + 1]; j2 = csr_src[pb + 2]; j3 = csr_src[pb + 3];
    while (p + 3 < e) {
      uint4 n0 = *(const uint4*)(bp + (size_t)j0 * DH);   // data grp k+1 (idx ready)
      uint4 n1 = *(const uint4*)(bp + (size_t)j1 * DH);
      uint4 n2 = *(const uint4*)(bp + (size_t)j2 * DH);
      uint4 n3 = *(const uint4*)(bp + (size_t)j3 * DH);
      p += 4;
      int pb2 = (p + 3 < e) ? p : p - 4;                  // idx grp k+2
      j0 = csr_src[pb2]; j1 = csr_src[pb2 + 1]; j2 = csr_src[pb2 + 2]; j3 = csr_src[pb2 + 3];
      DEC4(c0); DEC4(c1); DEC4(c2); DEC4(c3);             // decode grp k
      c0 = n0; c1 = n1; c2 = n2; c3 = n3;
    }
    DEC4(c0); DEC4(c1); DEC4(c2); DEC4(c3);
  }
  for (; p < e; ++p) {
    uint4 u0 = *(const uint4*)(bp + (size_t)csr_src[p] * DH);
    DEC4(u0);
  }
}

// ---------------- build: LDS hist -> atomic range reservation -> place ------
// Bucketed (bucket = dst>>8, 391 buckets): confines pairs/csr scatters to
// 20KB L2-resident windows (R7: unbucketed scatter = 3x worse via write
// amplification). Blocks 0-2 also do the coalesced LDS-tile W-transpose
// (R10 lesson: grid=391 on 256 CUs -> LDS occupancy cap NOT binding, and
// scatter-write transpose elsewhere regressed; keep tile transpose here).

__global__ __launch_bounds__(256) void k_build(const int* __restrict__ esrc,
                                               const int* __restrict__ edst,
                                               const int* __restrict__ batch,
                                               const float* __restrict__ W0,
                                               const float* __restrict__ W1,
                                               const float* __restrict__ W2,
                                               int* __restrict__ bucketCursor,
                                               unsigned int* __restrict__ pairs,
                                               int* __restrict__ startg,
                                               _Float16* __restrict__ Wt) {
  __shared__ _Float16 tile[128][LDH];
  __shared__ int h[NBUCK];
  __shared__ int cur[NBUCK];
  int b = blockIdx.x, t = threadIdx.x;
  int gtid = b * 256 + t;

  if (b < 3) {   // W transpose, coalesced both directions
    const float* W = (b == 0) ? W0 : (b == 1) ? W1 : W2;
#pragma unroll
    for (int i = 0; i < 64; ++i) {
      int idx = i * 256 + t;
      int r = idx >> 7, c = idx & 127;
      tile[c][r] = (_Float16)W[r * DH + c];
    }
    __syncthreads();
#pragma unroll
    for (int i = 0; i < 8; ++i) {
      int idx = i * 256 + t;
      int n = idx >> 4, c = (idx & 15) * 8;
      *(half8*)&Wt[(size_t)b * DH * DH + n * DH + c] = *(const half8*)&tile[n][c];
    }
  }

  if (gtid < NN) {
    int bat = batch[gtid];
    int prev = (gtid == 0) ? -1 : batch[gtid - 1];
    for (int g = prev + 1; g <= bat; ++g) startg[g] = gtid;
    if (gtid == NN - 1)
      for (int g = bat + 1; g <= NG; ++g) startg[g] = NN;
  }

  for (int i = t; i < NBUCK; i += 256) h[i] = 0;
  __syncthreads();
  int base = b * EPB;
  int dv[EPB / 256];   // cache dst values: placement pass re-uses w/o re-load
#pragma unroll
  for (int i = 0; i < EPB / 256; ++i) {
    int e = base + i * 256 + t;
    dv[i] = (e < NE) ? edst[e] : -1;
    if (e < NE) atomicAdd(&h[dv[i] >> 8], 1);
  }
  __syncthreads();
  for (int i = t; i < NBUCK; i += 256) {
    int rel = atomicAdd(&bucketCursor[i], h[i]);   // reserve contiguous range
    cur[i] = i * CAP + rel;
  }
  __syncthreads();
#pragma unroll
  for (int i = 0; i < EPB / 256; ++i) {
    int e = base + i * 256 + t;
    if (e < NE) {
      int d = dv[i];
      int q = atomicAdd(&cur[d >> 8], 1);
      pairs[q] = ((unsigned int)esrc[e] << 8) | (unsigned int)(d & 255);
    }
  }
}

// ---------------- finalize: per-bucket count/scan -> offA/offB/dinv + csr ---
// 391 blocks (full GPU), 1 node/thread.

__global__ __launch_bounds__(256) void k_finalize(const unsigned int* __restrict__ pairs,
                                                  const int* __restrict__ bucketCursor,
                                                  int* __restrict__ offA,
                                                  int* __restrict__ offB,
                                                  float* __restrict__ dinv,
                                                  int* __restrict__ csr_src) {
  __shared__ int cnt[256];
  __shared__ int tsum[256];
  int b = blockIdx.x, t = threadIdx.x;
  int g = (b << 8) + t;
  cnt[t] = 0;
  __syncthreads();
  int pStart = b * CAP;
  int pEnd = pStart + bucketCursor[b];
  for (int p = pStart + t; p < pEnd; p += 256)
    atomicAdd(&cnt[pairs[p] & 255], 1);
  __syncthreads();
  int c = cnt[t];
  tsum[t] = c;
  __syncthreads();
  for (int off = 1; off < 256; off <<= 1) {
    int v = (t >= off) ? tsum[t - off] : 0;
    __syncthreads();
    tsum[t] += v;
    __syncthreads();
  }
  int basep = pStart + ((t > 0) ? tsum[t - 1] : 0);
  if (g < NN) {
    offA[g] = basep;
    offB[g] = basep + c;
    dinv[g] = rsqrtf((float)c + 1.f);
  }
  cnt[t] = basep;
  __syncthreads();
  for (int p = pStart + t; p < pEnd; p += 256) {
    unsigned int pr = pairs[p];
    int pos = atomicAdd(&cnt[pr & 255], 1);
    csr_src[pos] = (int)(pr >> 8);
  }
}

// ---------------- MFMA GEMM (layer 1): Out8 = e5m2(dinv[r]*(x @ W1)) --------

template <bool F32IN>
__global__ __launch_bounds__(256) void k_gemm(const void* __restrict__ Ap,
                                              const _Float16* __restrict__ Wt,
                                              const float* __restrict__ dinv,
                                              unsigned char* __restrict__ Out8) {
  __shared__ _Float16 Wl[128 * LDH];
  int tid = threadIdx.x;
  int rowBase = blockIdx.x * 128;

#pragma unroll
  for (int i = 0; i < 8; ++i) {
    int chunk = tid + i * 256;
    int r = chunk >> 4, c = (chunk & 15) * 8;
    *(half8*)&Wl[r * LDH + c] = *(const half8*)(Wt + r * DH + c);
  }

  int wv = tid >> 6;
  int lane = tid & 63;
  int n16 = lane & 15;
  int quad = lane >> 4;

  int r0 = rowBase + wv * 32 + n16;
  int r1 = r0 + 16;

  half8 af[2][4];
  if (F32IN) {
    const float* A = (const float*)Ap;
#pragma unroll
    for (int kk = 0; kk < 4; ++kk) {
      half8 z = {};
      if (r0 < NN) {
        float4 lo = *(const float4*)(A + (size_t)r0 * DH + quad * 8 + kk * 32);
        float4 hi = *(const float4*)(A + (size_t)r0 * DH + quad * 8 + kk * 32 + 4);
        z = (half8){(_Float16)lo.x, (_Float16)lo.y, (_Float16)lo.z, (_Float16)lo.w,
                    (_Float16)hi.x, (_Float16)hi.y, (_Float16)hi.z, (_Float16)hi.w};
      }
      af[0][kk] = z;
      half8 z1 = {};
      if (r1 < NN) {
        float4 lo = *(const float4*)(A + (size_t)r1 * DH + quad * 8 + kk * 32);
        float4 hi = *(const float4*)(A + (size_t)r1 * DH + quad * 8 + kk * 32 + 4);
        z1 = (half8){(_Float16)lo.x, (_Float16)lo.y, (_Float16)lo.z, (_Float16)lo.w,
                     (_Float16)hi.x, (_Float16)hi.y, (_Float16)hi.z, (_Float16)hi.w};
      }
      af[1][kk] = z1;
    }
  } else {
    const _Float16* A = (const _Float16*)Ap;
#pragma unroll
    for (int kk = 0; kk < 4; ++kk) {
      half8 z = {};
      if (r0 < NN) z = *(const half8*)(A + (size_t)r0 * DH + quad * 8 + kk * 32);
      af[0][kk] = z;
      half8 z1 = {};
      if (r1 < NN) z1 = *(const half8*)(A + (size_t)r1 * DH + quad * 8 + kk * 32);
      af[1][kk] = z1;
    }
  }
  __syncthreads();

  f32x4 acc[2][8];
#pragma unroll
  for (int mt = 0; mt < 2; ++mt)
#pragma unroll
    for (int ct = 0; ct < 8; ++ct) acc[mt][ct] = (f32x4){0.f, 0.f, 0.f, 0.f};

  const _Float16* bp = &Wl[n16 * LDH + quad * 8];
#pragma unroll
  for (int kk = 0; kk < 4; ++kk) {
#pragma unroll
    for (int ct = 0; ct < 8; ++ct) {
      half8 bf = *(const half8*)(bp + (size_t)ct * 16 * LDH + kk * 32);
      acc[0][ct] = __builtin_amdgcn_mfma_f32_16x16x32_f16(af[0][kk], bf, acc[0][ct], 0, 0, 0);
      acc[1][ct] = __builtin_amdgcn_mfma_f32_16x16x32_f16(af[1][kk], bf, acc[1][ct], 0, 0, 0);
    }
  }

  float dv[2][4];
#pragma unroll
  for (int mt = 0; mt < 2; ++mt)
#pragma unroll
    for (int r = 0; r < 4; ++r) {
      int gr = rowBase + wv * 32 + mt * 16 + quad * 4 + r;
      dv[mt][r] = (gr < NN) ? dinv[gr] : 0.f;
    }

  __syncthreads();
#pragma unroll
  for (int mt = 0; mt < 2; ++mt)
#pragma unroll
    for (int ct = 0; ct < 8; ++ct)
#pragma unroll
      for (int r = 0; r < 4; ++r)
        Wl[(wv * 32 + mt * 16 + quad * 4 + r) * LDH + ct * 16 + n16] =
            (_Float16)(acc[mt][ct][r] * dv[mt][r]);
  __syncthreads();

#pragma unroll
  for (int i = 0; i < 8; ++i) {
    int chunk = tid + i * 256;
    int r = chunk >> 4, c = (chunk & 15) * 8;
    int gr = rowBase + r;
    if (gr < NN) {
      half8 v = *(const half8*)&Wl[r * LDH + c];
      unsigned int lo = enc8(v[0]) | (enc8(v[1]) << 8) | (enc8(v[2]) << 16) | (enc8(v[3]) << 24);
      unsigned int hi = enc8(v[4]) | (enc8(v[5]) << 8) | (enc8(v[6]) << 16) | (enc8(v[7]) << 24);
      uint2 st = {lo, hi};
      *(uint2*)(Out8 + (size_t)gr * DH + c) = st;
    }
  }
}

// ---------------- fused aggregate_L + pool_L + GEMM_{L+1} ----------------

__global__ __launch_bounds__(512) void k_fused(const unsigned char* __restrict__ hs8_in,
                                               const int* __restrict__ csr_src,
                                               const int* __restrict__ offA,
                                               const int* __restrict__ offB,
                                               const float* __restrict__ dinv,
                                               const float* __restrict__ bias,
                                               const int* __restrict__ batch,
                                               const int* __restrict__ startg,
                                               float* __restrict__ pooled,
                                               int colOff,
                                               const _Float16* __restrict__ Wt,
                                               unsigned char* __restrict__ hs8_out) {
  __shared__ _Float16 Hl[64 * LDH];
  __shared__ _Float16 Wl[128 * LDH];
  int tid = threadIdx.x;
  int n0 = blockIdx.x * 64;

#pragma unroll
  for (int i = 0; i < 4; ++i) {
    int chunk = tid + i * 512;
    int r = chunk >> 4, c = (chunk & 15) * 8;
    *(half8*)&Wl[r * LDH + c] = *(const half8*)(Wt + r * DH + c);
  }

  int nd = tid >> 3;
  int part = tid & 7;
  int n = n0 + nd;
  bool valid = (n < NN);

  half2v acc[8];
#pragma unroll
  for (int i = 0; i < 8; ++i) acc[i] = (half2v){(_Float16)0, (_Float16)0};

  if (valid) {
    const unsigned char* bp = hs8_in + part * 16;
    uint4 us = *(const uint4*)(bp + (size_t)n * DH);
    DEC4(us);
    gather_rows(bp, csr_src, offA[n], offB[n], acc);
  }

  float dv = valid ? dinv[n] : 0.f;
#pragma unroll
  for (int w = 0; w < 4; ++w) {
    int dim = part * 16 + w * 4;
    float4 b4 = *(const float4*)(bias + dim);
    float h0 = valid ? fmaxf(fmaf((float)acc[2 * w][0], dv, b4.x), 0.f) : 0.f;
    float h1 = valid ? fmaxf(fmaf((float)acc[2 * w + 1][0], dv, b4.y), 0.f) : 0.f;
    float h2 = valid ? fmaxf(fmaf((float)acc[2 * w][1], dv, b4.z), 0.f) : 0.f;
    float h3 = valid ? fmaxf(fmaf((float)acc[2 * w + 1][1], dv, b4.w), 0.f) : 0.f;
    half4 hh = {(_Float16)h0, (_Float16)h1, (_Float16)h2, (_Float16)h3};
    *(half4*)&Hl[nd * LDH + dim] = hh;
  }
  __syncthreads();

  if (tid < DH) {
    int nEnd = (n0 + 64 < NN) ? n0 + 64 : NN;
    int gF = batch[n0];
    int gL = batch[nEnd - 1];
    for (int g = gF; g <= gL; ++g) {
      int rs = (startg[g] > n0) ? startg[g] : n0;
      int re = (startg[g + 1] < nEnd) ? startg[g + 1] : nEnd;
      if (re > rs) {
        float sum = 0.f;
        for (int r2 = rs; r2 < re; ++r2) sum += (float)Hl[(r2 - n0) * LDH + tid];
        atomicAdd(&pooled[g * (3 * DH) + colOff + tid], sum);
      }
    }
  }

  int wv = tid >> 6;
  int lane = tid & 63;
  int n16 = lane & 15;
  int quad = lane >> 4;
  int m16 = wv >> 1;
  int ctB = (wv & 1) * 4;

  f32x4 acc2[4];
#pragma unroll
  for (int ct = 0; ct < 4; ++ct) acc2[ct] = (f32x4){0.f, 0.f, 0.f, 0.f};

  const _Float16* ap = &Hl[(m16 * 16 + n16) * LDH + quad * 8];
#pragma unroll
  for (int kk = 0; kk < 4; ++kk) {
    half8 af = *(const half8*)(ap + kk * 32);
#pragma unroll
    for (int ct = 0; ct < 4; ++ct) {
      half8 bf = *(const half8*)&Wl[((ctB + ct) * 16 + n16) * LDH + quad * 8 + kk * 32];
      acc2[ct] = __builtin_amdgcn_mfma_f32_16x16x32_f16(af, bf, acc2[ct], 0, 0, 0);
    }
  }

  float dvo[4];
#pragma unroll
  for (int rr = 0; rr < 4; ++rr) {
    int gr = n0 + m16 * 16 + quad * 4 + rr;
    dvo[rr] = (gr < NN) ? dinv[gr] : 0.f;
  }

  __syncthreads();
#pragma unroll
  for (int ct = 0; ct < 4; ++ct)
#pragma unroll
    for (int rr = 0; rr < 4; ++rr)
      Hl[(m16 * 16 + quad * 4 + rr) * LDH + (ctB + ct) * 16 + n16] =
          (_Float16)(acc2[ct][rr] * dvo[rr]);
  __syncthreads();

#pragma unroll
  for (int i = 0; i < 2; ++i) {
    int chunk = tid + i * 512;
    int r = chunk >> 4, c = (chunk & 15) * 8;
    int gr = n0 + r;
    if (gr < NN) {
      half8 v = *(const half8*)&Hl[r * LDH + c];
      unsigned int lo = enc8(v[0]) | (enc8(v[1]) << 8) | (enc8(v[2]) << 16) | (enc8(v[3]) << 24);
      unsigned int hi = enc8(v[4]) | (enc8(v[5]) << 8) | (enc8(v[6]) << 16) | (enc8(v[7]) << 24);
      uint2 st = {lo, hi};
      *(uint2*)(hs8_out + (size_t)gr * DH + c) = st;
    }
  }
}

// ---------------- final aggregate + pool (pipelined gather) ----------------

__global__ __launch_bounds__(512) void k_aggregate(const unsigned char* __restrict__ hs8,
                                                   const int* __restrict__ csr_src,
                                                   const int* __restrict__ offA,
                                                   const int* __restrict__ offB,
                                                   const float* __restrict__ dinv,
                                                   const float* __restrict__ bias,
                                                   const int* __restrict__ batch,
                                                   const int* __restrict__ startg,
                                                   float* __restrict__ pooled,
                                                   int colOff) {
  __shared__ float stage[64][LDF];   // LDF=132 pad: spreads part-lanes across banks
  int tid = threadIdx.x;
  int n0 = blockIdx.x * 64;
  int nd = tid >> 3;
  int part = tid & 7;
  int n = n0 + nd;
  bool valid = (n < NN);

  half2v acc[8];
#pragma unroll
  for (int i = 0; i < 8; ++i) acc[i] = (half2v){(_Float16)0, (_Float16)0};

  if (valid) {
    const unsigned char* bp = hs8 + part * 16;
    uint4 us = *(const uint4*)(bp + (size_t)n * DH);
    DEC4(us);
    gather_rows(bp, csr_src, offA[n], offB[n], acc);
  }

  float dv = valid ? dinv[n] : 0.f;
#pragma unroll
  for (int w = 0; w < 4; ++w) {
    int dim = part * 16 + w * 4;
    float4 b4 = *(const float4*)(bias + dim);
    float4 r;
    r.x = valid ? fmaxf(fmaf((float)acc[2 * w][0], dv, b4.x), 0.f) : 0.f;
    r.y = valid ? fmaxf(fmaf((float)acc[2 * w + 1][0], dv, b4.y), 0.f) : 0.f;
    r.z = valid ? fmaxf(fmaf((float)acc[2 * w][1], dv, b4.z), 0.f) : 0.f;
    r.w = valid ? fmaxf(fmaf((float)acc[2 * w + 1][1], dv, b4.w), 0.f) : 0.f;
    *(float4*)&stage[nd][dim] = r;
  }
  __syncthreads();

  if (tid < DH) {
    int nEnd = (n0 + 64 < NN) ? n0 + 64 : NN;
    int gF = batch[n0];
    int gL = batch[nEnd - 1];
    for (int g = gF; g <= gL; ++g) {
      int rs = (startg[g] > n0) ? startg[g] : n0;
      int re = (startg[g + 1] < nEnd) ? startg[g + 1] : nEnd;
      if (re > rs) {
        float sum = 0.f;
        for (int r2 = rs; r2 < re; ++r2) sum += stage[r2 - n0][tid];
        atomicAdd(&pooled[g * (3 * DH) + colOff + tid], sum);
      }
    }
  }
}

// ---------------- head ----------------

__global__ __launch_bounds__(128) void k_head(const float* __restrict__ pooled,
                                              const int* __restrict__ startg,
                                              const float* __restrict__ l1w,
                                              const float* __restrict__ l1b,
                                              const float* __restrict__ l2w,
                                              const float* __restrict__ l2b,
                                              float* __restrict__ out) {
  __shared__ float pr[3 * DH];
  __shared__ float grow[DH];
  __shared__ float lg[16];
  int g = blockIdx.x, t = threadIdx.x;
  float cnt = (float)(startg[g + 1] - startg[g]);
  float inv = 1.0f / fmaxf(cnt, 1.0f);
  for (int k = t; k < 3 * DH; k += 128) pr[k] = pooled[g * (3 * DH) + k] * inv;
  __syncthreads();
  float acc = l1b[t];
  for (int k = 0; k < 3 * DH; ++k) acc = fmaf(pr[k], l1w[k * DH + t], acc);
  grow[t] = fmaxf(acc, 0.f);
  __syncthreads();
  if (t < 10) {
    float a = l2b[t];
    for (int k = 0; k < DH; ++k) a = fmaf(grow[k], l2w[k * 10 + t], a);
    lg[t] = a;
  }
  __syncthreads();
  if (t < 10) {
    float m = lg[0];
    for (int i = 1; i < 10; ++i) m = fmaxf(m, lg[i]);
    float sum = 0.f;
    for (int i = 0; i < 10; ++i) sum += expf(lg[i] - m);
    out[g * 10 + t] = lg[t] - m - logf(sum);
  }
}

// ---------------- launch ----------------

extern "C" void kernel_launch(void* const* d_in, const int* in_sizes, int n_in,
                              void* d_out, int out_size, void* d_ws, size_t ws_size,
                              hipStream_t stream) {
  const float* x = (const float*)d_in[0];
  const int* ei = (const int*)d_in[1];
  const int* esrc = ei;
  const int* edst = ei + NE;
  const int* batch = (const int*)d_in[2];
  const float* W0 = (const float*)d_in[4];
  const float* W1 = (const float*)d_in[6];
  const float* W2 = (const float*)d_in[8];
  const float* B[3] = {(const float*)d_in[5], (const float*)d_in[7], (const float*)d_in[9]};
  const float* l1w = (const float*)d_in[10];
  const float* l1b = (const float*)d_in[11];
  const float* l2w = (const float*)d_in[12];
  const float* l2b = (const float*)d_in[13];
  float* out = (float*)d_out;

  char* ws = (char*)d_ws;
  size_t off = 0;
  auto alloc = [&](size_t bytes) {
    char* p = ws + off;
    off = (off + bytes + 255) & ~(size_t)255;
    return p;
  };
  // memset region: pooled + bucketCursor (contiguous)
  float* pooled = (float*)alloc((size_t)NG * 3 * DH * 4);        // 98304 B
  int* bucketCursor = (int*)alloc(NBUCK * 4);                    // 1564 -> pad
  size_t msBytes = ((size_t)NG * 3 * DH * 4 + NBUCK * 4 + 255) & ~(size_t)255;

  int* offA = (int*)alloc((size_t)NN * 4);
  int* offB = (int*)alloc((size_t)NN * 4);
  float* dinv = (float*)alloc((size_t)NN * 4);
  int* startg = (int*)alloc((NG + 1) * 4);
  _Float16* Wt = (_Float16*)alloc((size_t)3 * DH * DH * 2);
  unsigned char* hs8A = (unsigned char*)alloc((size_t)NN * DH);
  unsigned char* hs8B = (unsigned char*)alloc((size_t)NN * DH);
  unsigned int* pairs = (unsigned int*)alloc((size_t)NBUCK * CAP * 4);
  int* csr_src = (int*)alloc((size_t)NBUCK * CAP * 4);

  hipMemsetAsync(pooled, 0, msBytes, stream);

  k_build<<<NBLK_BIN, 256, 0, stream>>>(esrc, edst, batch, W0, W1, W2,
                                        bucketCursor, pairs, startg, Wt);
  k_finalize<<<NBUCK, 256, 0, stream>>>(pairs, bucketCursor, offA, offB, dinv, csr_src);

  k_gemm<true><<<(NN + 127) / 128, 256, 0, stream>>>((const void*)x, Wt, dinv, hs8A);

  int nFusedBlk = (NN + 63) / 64;
  k_fused<<<nFusedBlk, 512, 0, stream>>>(hs8A, csr_src, offA, offB, dinv, B[0], batch,
                                         startg, pooled, 0,
                                         Wt + (size_t)1 * DH * DH, hs8B);
  k_fused<<<nFusedBlk, 512, 0, stream>>>(hs8B, csr_src, offA, offB, dinv, B[1], batch,
                                         startg, pooled, DH,
                                         Wt + (size_t)2 * DH * DH, hs8A);

  k_aggregate<<<nFusedBlk, 512, 0, stream>>>(hs8A, csr_src, offA, offB, dinv, B[2],
                                             batch, startg, pooled, 2 * DH);

  k_head<<<NG, 128, 0, stream>>>(pooled, startg, l1w, l1b, l2w, l2b, out);
}